// Round 8
// baseline (566.363 us; speedup 1.0000x reference)
//
#include <hip/hip_runtime.h>
#include <math.h>

#define KK 128
#define TT 512
#define BB 512
#define TAG_START 126
#define TAG_STOP 127

typedef float v4f __attribute__((ext_vector_type(4)));

// padded float index for the x vector: +4 floats every 32 -> the 16 distinct
// chunk addresses per read instr are at most 2-way bank-aliased (free).
#define XI(k) ((k) + (((k) >> 5) << 2))
#define XLEN 144

template <int CTRL>
__device__ __forceinline__ float dpp_add(float x) {
    int yi = __builtin_amdgcn_update_dpp(0, __float_as_int(x), CTRL, 0xF, 0xF, true);
    return x + __int_as_float(yi);
}
// sum over 16-lane group (lanes sharing l>>4): xor-butterfly with generators
// {1,2,15,8}: quad_perm swaps + row_mirror (xor15) + row_ror:8 (xor8). All DPP.
__device__ __forceinline__ float sum16(float x) {
    x = dpp_add<0xB1>(x);     // xor1  [1,0,3,2]
    x = dpp_add<0x4E>(x);     // xor2  [2,3,0,1]
    x = dpp_add<0x140>(x);    // row_mirror = xor15
    x = dpp_add<0x128>(x);    // row_ror:8  = xor8
    return x;
}

// ws layout: floats fwd [0,512), gold [512,1024); ints order [1024,1536)

// Descending-length rank (LPT schedule): order[r] = seq index with rank r.
__global__ __launch_bounds__(512) void order_kernel(const int* __restrict__ lengths,
                                                    int* __restrict__ order) {
    __shared__ int L[BB];
    int tid = threadIdx.x;
    L[tid] = lengths[tid];
    __syncthreads();
    int mylen = L[tid];
    int r = 0;
    for (int i = 0; i < BB; i++) {
        int li = L[i];
        r += (li > mylen) || (li == mylen && i < tid);
    }
    order[r] = tid;
}

// Blocks 0..511: forward recursion for seq b = order[blockIdx.x] (longest first).
//   512 threads = 8 waves. wave w, lane l: c = l&15 (col-group, 8 cols),
//   g = l>>4, rows r0..r0+3 with r0 = 16w+4g. Thread holds E[4 rows][8 cols]
//   in 32 regs (volatile-asm pinned). x read = 2 ds_read_b128/thread (4x fewer
//   LDS instr than R=1) reused across 4 rows; K-reduce = all-DPP 16-lane
//   butterfly; writers (c==0) emit one ds_write_b128 (4 packed rows) and exact
//   float4 em loads. ONE barrier/step; xs dbuf; em prefetch depth 4.
// Blocks 512..1023: gold score for seq b-512.
__global__ __launch_bounds__(512, 4) void fused_kernel(
    const float* __restrict__ feats, const float* __restrict__ trans,
    const int* __restrict__ tags, const int* __restrict__ lengths,
    const int* __restrict__ order,
    float* __restrict__ fwd_out, float* __restrict__ gold_out) {
    int tid = threadIdx.x;

    if (blockIdx.x < BB) {
        // ---------------- forward path ----------------
        int b = order[blockIdx.x];
        int w = tid >> 6;
        int l = tid & 63;
        int c = l & 15;          // col-group: cols 8c..8c+7
        int g = l >> 4;          // row-group within wave
        int r0 = 16 * w + 4 * g; // rows r0..r0+3

        __shared__ __align__(16) float xs[2][XLEN];
        __shared__ float As2[2];
        __shared__ float redm[8], reds[8];

        // --- pin E slice (4 rows x 8 cols) via volatile asm loads ---
        v4f tv[8];
#pragma unroll
        for (int r = 0; r < 4; r++) {
            const float* tp = trans + (r0 + r) * KK + 8 * c;
            asm volatile("global_load_dwordx4 %0, %1, off" : "=v"(tv[2 * r]) : "v"(tp));
            asm volatile("global_load_dwordx4 %0, %1, off" : "=v"(tv[2 * r + 1]) : "v"(tp + 4));
        }
        int len = lengths[b];
        const float* fbr4 = feats + (size_t)b * TT * KK + r0;
        asm volatile("s_waitcnt vmcnt(0)"
                     : "+v"(tv[0]), "+v"(tv[1]), "+v"(tv[2]), "+v"(tv[3]),
                       "+v"(tv[4]), "+v"(tv[5]), "+v"(tv[6]), "+v"(tv[7]));

        // per-row max over the 16-lane col-group (setup only; generic shfl ok)
        float Mj[4];
#pragma unroll
        for (int r = 0; r < 4; r++) {
            v4f a = tv[2 * r], bv = tv[2 * r + 1];
            float m = fmaxf(fmaxf(fmaxf(a.x, a.y), fmaxf(a.z, a.w)),
                            fmaxf(fmaxf(bv.x, bv.y), fmaxf(bv.z, bv.w)));
            m = fmaxf(m, __shfl_xor(m, 1));
            m = fmaxf(m, __shfl_xor(m, 2));
            m = fmaxf(m, __shfl_xor(m, 4));
            m = fmaxf(m, __shfl_xor(m, 8));
            Mj[r] = m;
        }
        v4f Ev[8];
#pragma unroll
        for (int i = 0; i < 8; i++) {
            float m = Mj[i >> 1];
            Ev[i].x = __expf(tv[i].x - m);
            Ev[i].y = __expf(tv[i].y - m);
            Ev[i].z = __expf(tv[i].z - m);
            Ev[i].w = __expf(tv[i].w - m);
        }

        // init x(0) = exp(alpha0 - 0)
        if (tid < KK) xs[0][XI(tid)] = (tid == TAG_START) ? 1.0f : 0.0f;
        if (tid == 0) { As2[0] = 0.f; As2[1] = 0.f; }

        float A = 0.f;
        float al[4] = {0.f, 0.f, 0.f, 0.f};
        float4 emb[4];
        if (c == 0) {
#pragma unroll
            for (int d = 0; d < 4; d++) {
                int tf = (d < len) ? d : (len - 1);
                emb[d] = *(const float4*)(fbr4 + (size_t)tf * KK);
            }
        }
        __syncthreads();

        int xbase = XI(8 * c);   // 8c + 4*(c>>2), pad-safe (chunk never crosses pad)
        int wbase = XI(r0);      // write base, 16B-aligned, pad-safe
        int tmax = (len + 3) & ~3;
        for (int t0 = 0; t0 < tmax; t0 += 4) {
#pragma unroll
            for (int d = 0; d < 4; d++) {
                int t = t0 + d;
                if (t < len) {                      // block-uniform guard
                    int cur = t & 1, nxt = cur ^ 1;
                    float Sn = As2[nxt];            // alpha_0(t-1): shift of x(t+1)
                    const v4f* xp = (const v4f*)(xs[cur] + xbase);
                    v4f xa = xp[0], xb = xp[1];     // 8 x values, reused 4 rows
                    float y[4];
#pragma unroll
                    for (int r = 0; r < 4; r++) {
                        v4f e0 = Ev[2 * r], e1 = Ev[2 * r + 1];
                        float p = e0.x * xa.x;
                        float q = e0.y * xa.y;
                        p = fmaf(e0.z, xa.z, p);
                        q = fmaf(e0.w, xa.w, q);
                        p = fmaf(e1.x, xb.x, p);
                        q = fmaf(e1.y, xb.y, q);
                        p = fmaf(e1.z, xb.z, p);
                        q = fmaf(e1.w, xb.w, q);
                        y[r] = p + q;
                    }
#pragma unroll
                    for (int r = 0; r < 4; r++) y[r] = sum16(y[r]);  // all-DPP

                    if (c == 0) {
                        float4 em = emb[d];
                        int tf = (t + 4 < len) ? (t + 4) : (len - 1);
                        emb[d] = *(const float4*)(fbr4 + (size_t)tf * KK);
                        float b0 = em.x + Mj[0] + A, b1 = em.y + Mj[1] + A;
                        float b2 = em.z + Mj[2] + A, b3 = em.w + Mj[3] + A;
                        v4f xn;
                        xn.x = y[0] * __expf(b0 - Sn);
                        xn.y = y[1] * __expf(b1 - Sn);
                        xn.z = y[2] * __expf(b2 - Sn);
                        xn.w = y[3] * __expf(b3 - Sn);
                        *(v4f*)(xs[nxt] + wbase) = xn;   // one b128 write
                        al[0] = b0 + __logf(y[0]);
                        al[1] = b1 + __logf(y[1]);
                        al[2] = b2 + __logf(y[2]);
                        al[3] = b3 + __logf(y[3]);
                        if (tid == 0) As2[cur] = al[0];  // row 0 -> shift t+1
                    }
                    A = Sn;
                    __syncthreads();                // single barrier per step
                }
            }
        }

        // terminal logsumexp_j( alpha[j] + trans[STOP,j] ); c==0 lanes hold 4 rows
        float m = -1e30f, s = 0.f;
        float t0v = 0.f, t1v = 0.f, t2v = 0.f, t3v = 0.f;
        if (c == 0) {
            float4 ts = *(const float4*)(trans + TAG_STOP * KK + r0);
            t0v = al[0] + ts.x;
            t1v = al[1] + ts.y;
            t2v = al[2] + ts.z;
            t3v = al[3] + ts.w;
            m = fmaxf(fmaxf(t0v, t1v), fmaxf(t2v, t3v));
        }
#pragma unroll
        for (int off = 32; off >= 1; off >>= 1) m = fmaxf(m, __shfl_xor(m, off));
        if (c == 0)
            s = __expf(t0v - m) + __expf(t1v - m) + __expf(t2v - m) + __expf(t3v - m);
#pragma unroll
        for (int off = 32; off >= 1; off >>= 1) s += __shfl_xor(s, off);
        if (l == 0) { redm[w] = m; reds[w] = s; }
        __syncthreads();
        if (tid == 0) {
            float M2 = redm[0];
            for (int i = 1; i < 8; i++) M2 = fmaxf(M2, redm[i]);
            float S2 = 0.f;
            for (int i = 0; i < 8; i++) S2 += reds[i] * __expf(redm[i] - M2);
            fwd_out[b] = M2 + __logf(S2);
        }
    } else {
        // ---------------- gold path ----------------
        int b = blockIdx.x - BB;
        int len = lengths[b];
        const int* tg = tags + (size_t)b * TT;
        const float* fb = feats + (size_t)b * TT * KK;
        float acc = 0.f;
        for (int i = tid; i <= len; i += 512) {
            int from = (i == 0) ? TAG_START : tg[i - 1];
            int to = (i < len) ? tg[i] : TAG_STOP;
            acc += trans[to * KK + from];
        }
        for (int t = tid; t < len; t += 512)
            acc += fb[(size_t)t * KK + tg[t]];
        __shared__ float sred[8];
#pragma unroll
        for (int off = 32; off >= 1; off >>= 1) acc += __shfl_xor(acc, off);
        if ((tid & 63) == 0) sred[tid >> 6] = acc;
        __syncthreads();
        if (tid == 0) {
            float s = 0.f;
            for (int i = 0; i < 8; i++) s += sred[i];
            gold_out[b] = s;
        }
    }
}

__global__ __launch_bounds__(512) void final_kernel(const float* __restrict__ fwd_s,
                                                    const float* __restrict__ gold_s,
                                                    float* __restrict__ out) {
    int tid = threadIdx.x;
    float v = fabsf(fwd_s[tid] - gold_s[tid]);
#pragma unroll
    for (int off = 32; off >= 1; off >>= 1) v += __shfl_xor(v, off);
    __shared__ float sred[8];
    if ((tid & 63) == 0) sred[tid >> 6] = v;
    __syncthreads();
    if (tid == 0) {
        float s = 0.f;
        for (int i = 0; i < 8; i++) s += sred[i];
        out[0] = s / (float)BB;
    }
}

extern "C" void kernel_launch(void* const* d_in, const int* in_sizes, int n_in,
                              void* d_out, int out_size, void* d_ws, size_t ws_size,
                              hipStream_t stream) {
    const float* feats = (const float*)d_in[0];
    const float* trans = (const float*)d_in[1];
    const int* tags = (const int*)d_in[2];
    const int* lengths = (const int*)d_in[3];

    float* ws = (float*)d_ws;
    float* fwdv = ws;
    float* goldv = ws + BB;
    int* order = (int*)(ws + 2 * BB);

    order_kernel<<<1, 512, 0, stream>>>(lengths, order);
    fused_kernel<<<2 * BB, 512, 0, stream>>>(feats, trans, tags, lengths, order,
                                             fwdv, goldv);
    final_kernel<<<1, 512, 0, stream>>>(fwdv, goldv, (float*)d_out);
}

// Round 9
// 473.899 us; speedup vs baseline: 1.1951x; 1.1951x over previous
//
#include <hip/hip_runtime.h>
#include <math.h>

#define KK 128
#define TT 512
#define BB 512
#define TAG_START 126
#define TAG_STOP 127

typedef float v4f __attribute__((ext_vector_type(4)));

// padded x index: +4 floats every 16 -> 16-float chunk c starts at 80c bytes;
// the 8 distinct 16B reads per instruction tile the 128B bank space exactly.
#define XI(k) ((k) + (((k) >> 4) << 2))
#define XLEN 160

template <int CTRL>
__device__ __forceinline__ float dpp_add(float x) {
    int yi = __builtin_amdgcn_update_dpp(0, __float_as_int(x), CTRL, 0xF, 0xF, true);
    return x + __int_as_float(yi);
}
// sum over 8-lane group (same l>>3): xor1, xor2 (quad_perm), then
// row_half_mirror (lane i -> i^7 within its 8-group) adds the other 4-subsum.
__device__ __forceinline__ float sum8(float x) {
    x = dpp_add<0xB1>(x);      // quad_perm [1,0,3,2] = xor1
    x = dpp_add<0x4E>(x);      // quad_perm [2,3,0,1] = xor2
    x = dpp_add<0x141>(x);     // row_half_mirror = xor7 within 8
    return x;
}

// ws layout: floats fwd [0,512), gold [512,1024); ints order [1024,1536)

// Descending-length rank (LPT schedule): order[r] = seq index with rank r.
__global__ __launch_bounds__(512) void order_kernel(const int* __restrict__ lengths,
                                                    int* __restrict__ order) {
    __shared__ int L[BB];
    int tid = threadIdx.x;
    L[tid] = lengths[tid];
    __syncthreads();
    int mylen = L[tid];
    int r = 0;
    for (int i = 0; i < BB; i++) {
        int li = L[i];
        r += (li > mylen) || (li == mylen && i < tid);
    }
    order[r] = tid;
}

// Blocks 0..511: forward recursion for seq b = order[blockIdx.x] (longest first).
//   512 threads = 8 waves. wave w, lane l: c = l&7 (cols 16c..16c+15),
//   g = l>>3, rows r0 = 16w+2g, r0+1. Thread holds E[2 rows][16 cols] in 32
//   regs (volatile-asm pinned). x read = 4 ds_read_b128/thread -> 32 read
//   instr/block-step (vs R7's 64), bank-footprint exactly 128B (0 conflicts).
//   K-reduce = all-DPP 8-lane butterfly; writers (c==0, 8/wave) pack 2 rows
//   into one ds_write_b64 and do only 2 exp + 2 log each (off the x chain:
//   x = y * exp(em+Mj+A-Sn), log feeds As/terminal only). ONE barrier/step;
//   xs dbuf; em = exact float2 prefetch depth 4 on writers.
// Blocks 512..1023: gold score for seq b-512.
__global__ __launch_bounds__(512, 4) void fused_kernel(
    const float* __restrict__ feats, const float* __restrict__ trans,
    const int* __restrict__ tags, const int* __restrict__ lengths,
    const int* __restrict__ order,
    float* __restrict__ fwd_out, float* __restrict__ gold_out) {
    int tid = threadIdx.x;

    if (blockIdx.x < BB) {
        // ---------------- forward path ----------------
        int b = order[blockIdx.x];
        int w = tid >> 6;
        int l = tid & 63;
        int c = l & 7;           // col-group: cols 16c..16c+15
        int g = l >> 3;          // row-pair within wave
        int r0 = 16 * w + 2 * g; // rows r0, r0+1

        __shared__ __align__(16) float xs[2][XLEN];
        __shared__ float As2[2];
        __shared__ float redm[8], reds[8];

        // --- pin E slice (2 rows x 16 cols) via volatile asm loads ---
        v4f tv[8];
#pragma unroll
        for (int r = 0; r < 2; r++) {
            const float* tp = trans + (r0 + r) * KK + 16 * c;
            asm volatile("global_load_dwordx4 %0, %1, off" : "=v"(tv[4 * r + 0]) : "v"(tp));
            asm volatile("global_load_dwordx4 %0, %1, off" : "=v"(tv[4 * r + 1]) : "v"(tp + 4));
            asm volatile("global_load_dwordx4 %0, %1, off" : "=v"(tv[4 * r + 2]) : "v"(tp + 8));
            asm volatile("global_load_dwordx4 %0, %1, off" : "=v"(tv[4 * r + 3]) : "v"(tp + 12));
        }
        int len = lengths[b];
        const float* fbr2 = feats + (size_t)b * TT * KK + r0;
        asm volatile("s_waitcnt vmcnt(0)"
                     : "+v"(tv[0]), "+v"(tv[1]), "+v"(tv[2]), "+v"(tv[3]),
                       "+v"(tv[4]), "+v"(tv[5]), "+v"(tv[6]), "+v"(tv[7]));

        // per-row max over 16 local cols + 8-lane col-groups (setup only)
        float Mj[2];
#pragma unroll
        for (int r = 0; r < 2; r++) {
            float m = -1e30f;
#pragma unroll
            for (int i = 0; i < 4; i++) {
                v4f a = tv[4 * r + i];
                m = fmaxf(m, fmaxf(fmaxf(a.x, a.y), fmaxf(a.z, a.w)));
            }
            m = fmaxf(m, __shfl_xor(m, 1));
            m = fmaxf(m, __shfl_xor(m, 2));
            m = fmaxf(m, __shfl_xor(m, 4));
            Mj[r] = m;
        }
        v4f Ev[8];
#pragma unroll
        for (int i = 0; i < 8; i++) {
            float m = Mj[i >> 2];
            Ev[i].x = __expf(tv[i].x - m);
            Ev[i].y = __expf(tv[i].y - m);
            Ev[i].z = __expf(tv[i].z - m);
            Ev[i].w = __expf(tv[i].w - m);
        }

        // init x(0) = exp(alpha0 - 0)
        if (tid < KK) xs[0][XI(tid)] = (tid == TAG_START) ? 1.0f : 0.0f;
        if (tid == 0) { As2[0] = 0.f; As2[1] = 0.f; }

        float A = 0.f;
        float al0 = 0.f, al1 = 0.f;
        float2 emb[4];
        if (c == 0) {
#pragma unroll
            for (int d = 0; d < 4; d++) {
                int tf = (d < len) ? d : (len - 1);
                emb[d] = *(const float2*)(fbr2 + (size_t)tf * KK);
            }
        }
        __syncthreads();

        int xbase = 20 * c;          // XI(16c)
        int wbase = 20 * w + 2 * g;  // XI(r0)
        int tmax = (len + 3) & ~3;
        for (int t0 = 0; t0 < tmax; t0 += 4) {
#pragma unroll
            for (int d = 0; d < 4; d++) {
                int t = t0 + d;
                if (t < len) {                      // block-uniform guard
                    int cur = t & 1, nxt = cur ^ 1;
                    float Sn = As2[nxt];            // alpha_0(t-1): shift of x(t+1)
                    const v4f* xp = (const v4f*)(xs[cur] + xbase);
                    v4f x0 = xp[0], x1 = xp[1], x2 = xp[2], x3 = xp[3];
                    float y0, y1;
                    {
                        v4f e0 = Ev[0], e1 = Ev[1], e2 = Ev[2], e3 = Ev[3];
                        float p = e0.x * x0.x, q = e0.y * x0.y;
                        p = fmaf(e0.z, x0.z, p); q = fmaf(e0.w, x0.w, q);
                        p = fmaf(e1.x, x1.x, p); q = fmaf(e1.y, x1.y, q);
                        p = fmaf(e1.z, x1.z, p); q = fmaf(e1.w, x1.w, q);
                        p = fmaf(e2.x, x2.x, p); q = fmaf(e2.y, x2.y, q);
                        p = fmaf(e2.z, x2.z, p); q = fmaf(e2.w, x2.w, q);
                        p = fmaf(e3.x, x3.x, p); q = fmaf(e3.y, x3.y, q);
                        p = fmaf(e3.z, x3.z, p); q = fmaf(e3.w, x3.w, q);
                        y0 = p + q;
                    }
                    {
                        v4f e0 = Ev[4], e1 = Ev[5], e2 = Ev[6], e3 = Ev[7];
                        float p = e0.x * x0.x, q = e0.y * x0.y;
                        p = fmaf(e0.z, x0.z, p); q = fmaf(e0.w, x0.w, q);
                        p = fmaf(e1.x, x1.x, p); q = fmaf(e1.y, x1.y, q);
                        p = fmaf(e1.z, x1.z, p); q = fmaf(e1.w, x1.w, q);
                        p = fmaf(e2.x, x2.x, p); q = fmaf(e2.y, x2.y, q);
                        p = fmaf(e2.z, x2.z, p); q = fmaf(e2.w, x2.w, q);
                        p = fmaf(e3.x, x3.x, p); q = fmaf(e3.y, x3.y, q);
                        p = fmaf(e3.z, x3.z, p); q = fmaf(e3.w, x3.w, q);
                        y1 = p + q;
                    }
                    y0 = sum8(y0);                  // all-DPP, no DS pipe
                    y1 = sum8(y1);

                    if (c == 0) {
                        float2 em = emb[d];
                        int tf = (t + 4 < len) ? (t + 4) : (len - 1);
                        emb[d] = *(const float2*)(fbr2 + (size_t)tf * KK);
                        float b0 = em.x + Mj[0] + A;
                        float b1 = em.y + Mj[1] + A;
                        float2 xn;
                        xn.x = y0 * __expf(b0 - Sn);   // = exp(alpha - Sn)
                        xn.y = y1 * __expf(b1 - Sn);
                        *(float2*)(xs[nxt] + wbase) = xn;  // one b64, banks distinct
                        al0 = b0 + __logf(y0);         // off-chain: As/terminal
                        al1 = b1 + __logf(y1);
                        if (tid == 0) As2[cur] = al0;  // row 0 -> shift t+1
                    }
                    A = Sn;
                    __syncthreads();                // single barrier per step
                }
            }
        }

        // terminal logsumexp_j( alpha[j] + trans[STOP,j] ); c==0 lanes hold 2 rows
        float m = -1e30f, s = 0.f;
        float t0v = 0.f, t1v = 0.f;
        if (c == 0) {
            float2 ts = *(const float2*)(trans + TAG_STOP * KK + r0);
            t0v = al0 + ts.x;
            t1v = al1 + ts.y;
            m = fmaxf(t0v, t1v);
        }
#pragma unroll
        for (int off = 32; off >= 1; off >>= 1) m = fmaxf(m, __shfl_xor(m, off));
        if (c == 0) s = __expf(t0v - m) + __expf(t1v - m);
#pragma unroll
        for (int off = 32; off >= 1; off >>= 1) s += __shfl_xor(s, off);
        if (l == 0) { redm[w] = m; reds[w] = s; }
        __syncthreads();
        if (tid == 0) {
            float M2 = redm[0];
            for (int i = 1; i < 8; i++) M2 = fmaxf(M2, redm[i]);
            float S2 = 0.f;
            for (int i = 0; i < 8; i++) S2 += reds[i] * __expf(redm[i] - M2);
            fwd_out[b] = M2 + __logf(S2);
        }
    } else {
        // ---------------- gold path ----------------
        int b = blockIdx.x - BB;
        int len = lengths[b];
        const int* tg = tags + (size_t)b * TT;
        const float* fb = feats + (size_t)b * TT * KK;
        float acc = 0.f;
        for (int i = tid; i <= len; i += 512) {
            int from = (i == 0) ? TAG_START : tg[i - 1];
            int to = (i < len) ? tg[i] : TAG_STOP;
            acc += trans[to * KK + from];
        }
        for (int t = tid; t < len; t += 512)
            acc += fb[(size_t)t * KK + tg[t]];
        __shared__ float sred[8];
#pragma unroll
        for (int off = 32; off >= 1; off >>= 1) acc += __shfl_xor(acc, off);
        if ((tid & 63) == 0) sred[tid >> 6] = acc;
        __syncthreads();
        if (tid == 0) {
            float s = 0.f;
            for (int i = 0; i < 8; i++) s += sred[i];
            gold_out[b] = s;
        }
    }
}

__global__ __launch_bounds__(512) void final_kernel(const float* __restrict__ fwd_s,
                                                    const float* __restrict__ gold_s,
                                                    float* __restrict__ out) {
    int tid = threadIdx.x;
    float v = fabsf(fwd_s[tid] - gold_s[tid]);
#pragma unroll
    for (int off = 32; off >= 1; off >>= 1) v += __shfl_xor(v, off);
    __shared__ float sred[8];
    if ((tid & 63) == 0) sred[tid >> 6] = v;
    __syncthreads();
    if (tid == 0) {
        float s = 0.f;
        for (int i = 0; i < 8; i++) s += sred[i];
        out[0] = s / (float)BB;
    }
}

extern "C" void kernel_launch(void* const* d_in, const int* in_sizes, int n_in,
                              void* d_out, int out_size, void* d_ws, size_t ws_size,
                              hipStream_t stream) {
    const float* feats = (const float*)d_in[0];
    const float* trans = (const float*)d_in[1];
    const int* tags = (const int*)d_in[2];
    const int* lengths = (const int*)d_in[3];

    float* ws = (float*)d_ws;
    float* fwdv = ws;
    float* goldv = ws + BB;
    int* order = (int*)(ws + 2 * BB);

    order_kernel<<<1, 512, 0, stream>>>(lengths, order);
    fused_kernel<<<2 * BB, 512, 0, stream>>>(feats, trans, tags, lengths, order,
                                             fwdv, goldv);
    final_kernel<<<1, 512, 0, stream>>>(fwdv, goldv, (float*)d_out);
}